// Round 1
// baseline (2487.024 us; speedup 1.0000x reference)
//
#include <hip/hip_runtime.h>
#include <hip/hip_bf16.h>

typedef __bf16 bf16_t;
typedef __bf16 bf16x4 __attribute__((ext_vector_type(4)));
typedef __bf16 bf16x8 __attribute__((ext_vector_type(8)));
typedef float  f32x4  __attribute__((ext_vector_type(4)));

constexpr int T_ = 2048, H_ = 2048, I_ = 5632, E_ = 8, S_ = T_ * 2;

// ---- workspace layout (bytes) ----  total ~88.2 MB
constexpr size_t OFF_HB    = 0;                                   // bf16 hidden  [T][H]
constexpr size_t OFF_HOUT  = OFF_HB    + (size_t)T_ * H_ * 2;     // bf16 h       [S][I]
constexpr size_t OFF_DPART = OFF_HOUT  + (size_t)S_ * I_ * 2;     // f32 downpart [S][H]
constexpr size_t OFF_TOS   = OFF_DPART + (size_t)S_ * H_ * 4;     // int token_of_slot[S]
constexpr size_t OFF_SOT   = OFF_TOS   + (size_t)S_ * 4;          // int slot_of_tk[T*2]
constexpr size_t OFF_TKI   = OFF_SOT   + (size_t)S_ * 4;          // int topk_idx[T*2]
constexpr size_t OFF_TKW   = OFF_TKI   + (size_t)S_ * 4;          // f32 topk_w[T*2]
constexpr size_t OFF_CNT   = OFF_TKW   + (size_t)S_ * 4;          // int counts[E]
constexpr size_t OFF_OFFS  = OFF_CNT   + 64;                      // int offs[E]
constexpr size_t OFF_CUR   = OFF_OFFS  + 64;                      // int cursor[E]

// ================= router: logits, softmax, top-2, bf16 convert =================
__global__ __launch_bounds__(256)
void router_kernel(const float* __restrict__ hs, const float* __restrict__ gw,
                   int* __restrict__ tki, float* __restrict__ tkw,
                   int* __restrict__ counts, bf16_t* __restrict__ hb)
{
  const int t = blockIdx.x;
  const int tid = threadIdx.x;
  const int lane = tid & 63, wid = tid >> 6;
  const float* hrow = hs + (size_t)t * H_;
  const int c0 = tid * 8;
  float4 h0 = *(const float4*)(hrow + c0);
  float4 h1 = *(const float4*)(hrow + c0 + 4);
  bf16x8 hv;
  hv[0]=(bf16_t)h0.x; hv[1]=(bf16_t)h0.y; hv[2]=(bf16_t)h0.z; hv[3]=(bf16_t)h0.w;
  hv[4]=(bf16_t)h1.x; hv[5]=(bf16_t)h1.y; hv[6]=(bf16_t)h1.z; hv[7]=(bf16_t)h1.w;
  *(bf16x8*)(hb + (size_t)t * H_ + c0) = hv;

  float acc[E_];
  #pragma unroll
  for (int e = 0; e < E_; ++e) {
    const float* g = gw + (size_t)e * H_ + c0;
    float4 g0 = *(const float4*)(g);
    float4 g1 = *(const float4*)(g + 4);
    acc[e] = h0.x*g0.x + h0.y*g0.y + h0.z*g0.z + h0.w*g0.w
           + h1.x*g1.x + h1.y*g1.y + h1.z*g1.z + h1.w*g1.w;
  }
  #pragma unroll
  for (int e = 0; e < E_; ++e)
    #pragma unroll
    for (int o = 32; o > 0; o >>= 1)
      acc[e] += __shfl_down(acc[e], o);
  __shared__ float red[4][E_];
  if (lane == 0)
    #pragma unroll
    for (int e = 0; e < E_; ++e) red[wid][e] = acc[e];
  __syncthreads();
  if (tid == 0) {
    float l[E_];
    #pragma unroll
    for (int e = 0; e < E_; ++e) l[e] = red[0][e] + red[1][e] + red[2][e] + red[3][e];
    float m = l[0];
    #pragma unroll
    for (int e = 1; e < E_; ++e) m = fmaxf(m, l[e]);
    float p[E_]; float s = 0.f;
    #pragma unroll
    for (int e = 0; e < E_; ++e) { p[e] = __expf(l[e] - m); s += p[e]; }
    int i1 = 0;
    #pragma unroll
    for (int e = 1; e < E_; ++e) if (l[e] > l[i1]) i1 = e;   // strict > : ties -> lower idx (matches top_k)
    int i2 = (i1 == 0) ? 1 : 0;
    #pragma unroll
    for (int e = 0; e < E_; ++e) if (e != i1 && l[e] > l[i2]) i2 = e;
    tki[2*t] = i1; tki[2*t+1] = i2;
    tkw[2*t] = p[i1] / s; tkw[2*t+1] = p[i2] / s;
    atomicAdd(&counts[i1], 1);
    atomicAdd(&counts[i2], 1);
  }
}

// ================= scan: expert offsets + slot lists =================
__global__ void scan_kernel(const int* __restrict__ counts, const int* __restrict__ tki,
                            int* __restrict__ offs, int* __restrict__ cursor,
                            int* __restrict__ tos, int* __restrict__ sot)
{
  if (threadIdx.x == 0) {
    int run = 0;
    for (int e = 0; e < E_; ++e) { offs[e] = run; cursor[e] = run; run += counts[e]; }
  }
  __syncthreads();
  for (int t = threadIdx.x; t < T_; t += blockDim.x) {
    #pragma unroll
    for (int k = 0; k < 2; ++k) {
      int e = tki[2*t + k];
      int s = atomicAdd(&cursor[e], 1);
      tos[s] = t;
      sot[2*t + k] = s;
    }
  }
}

// ================= GEMM1: gathered hidden x w1^T, dual (gate,up) acc, fused silu*mul =================
// tile: BM=128 tokens x BNI=64 i-cols, BK=64. 4 waves, each 64x32 of BOTH gate and up.
constexpr int BM = 128, BNI = 64, BK = 64;

__global__ __launch_bounds__(256, 2)
void gemm1_kernel(const bf16_t* __restrict__ hb, const float* __restrict__ w1,
                  const int* __restrict__ tos, const int* __restrict__ offs,
                  const int* __restrict__ counts, bf16_t* __restrict__ hout)
{
  const int e = blockIdx.z;
  const int cnt = counts[e];
  const int m0 = blockIdx.x * BM;          // m innermost: m-tiles of same (n,e) run together -> L2/L3 reuse of B strip
  if (m0 >= cnt) return;
  const int off = offs[e];
  const int n0 = blockIdx.y * BNI;

  const float* Wg = w1 + (size_t)e * (2 * (size_t)I_ * H_) + (size_t)n0 * H_;
  const float* Wu = Wg + (size_t)I_ * H_;

  __shared__ bf16_t Al[2][BM][BK];      // 32 KB
  __shared__ bf16_t Bgl[2][BNI][BK];    // 16 KB
  __shared__ bf16_t Bul[2][BNI][BK];    // 16 KB

  const int tid = threadIdx.x;
  const int lane = tid & 63, wid = tid >> 6;
  const int wm = wid >> 1, wn = wid & 1;
  const int l15 = lane & 15, l4 = lane >> 4;

  // staging assignments (fixed per thread across K-steps)
  const bf16_t* asrc[4]; int arow_[4], akc_[4];
  #pragma unroll
  for (int c = 0; c < 4; ++c) {
    int q = tid + c * 256;          // 1024 chunks of 16B: row=q>>3 (8 chunks/row), kc=q&7
    int row = q >> 3, kc = q & 7;
    arow_[c] = row; akc_[c] = kc;
    int slot = off + m0 + row, mx = off + cnt - 1;
    if (slot > mx) slot = mx;       // clamp pad rows to a valid token
    asrc[c] = hb + (size_t)tos[slot] * H_ + kc * 8;
  }
  const float* bgsrc[4]; const float* busrc[4]; int brow_[4], bkc_[4];
  #pragma unroll
  for (int c = 0; c < 4; ++c) {
    int q = tid + c * 256;          // 1024 chunks of 16B f32: row=q>>4 (16 chunks/row), kc=q&15
    int row = q >> 4, kc = q & 15;
    brow_[c] = row; bkc_[c] = kc;
    bgsrc[c] = Wg + (size_t)row * H_ + kc * 4;
    busrc[c] = Wu + (size_t)row * H_ + kc * 4;
  }

  int4   ar[4]; float4 bgr[4]; float4 bur[4];
  auto load_regs = [&](int k0) {
    #pragma unroll
    for (int c = 0; c < 4; ++c) ar[c]  = *(const int4*)(asrc[c] + k0);
    #pragma unroll
    for (int c = 0; c < 4; ++c) bgr[c] = *(const float4*)(bgsrc[c] + k0);
    #pragma unroll
    for (int c = 0; c < 4; ++c) bur[c] = *(const float4*)(busrc[c] + k0);
  };
  auto write_lds = [&](int b) {
    #pragma unroll
    for (int c = 0; c < 4; ++c)
      *(int4*)&Al[b][arow_[c]][akc_[c] * 8] = ar[c];
    #pragma unroll
    for (int c = 0; c < 4; ++c) {
      bf16x4 t0; t0[0]=(bf16_t)bgr[c].x; t0[1]=(bf16_t)bgr[c].y; t0[2]=(bf16_t)bgr[c].z; t0[3]=(bf16_t)bgr[c].w;
      *(bf16x4*)&Bgl[b][brow_[c]][bkc_[c] * 4] = t0;
      bf16x4 t1; t1[0]=(bf16_t)bur[c].x; t1[1]=(bf16_t)bur[c].y; t1[2]=(bf16_t)bur[c].z; t1[3]=(bf16_t)bur[c].w;
      *(bf16x4*)&Bul[b][brow_[c]][bkc_[c] * 4] = t1;
    }
  };

  f32x4 accg[4][2], accu[4][2];
  #pragma unroll
  for (int mi = 0; mi < 4; ++mi)
    #pragma unroll
    for (int ni = 0; ni < 2; ++ni) {
      accg[mi][ni] = f32x4{0.f,0.f,0.f,0.f};
      accu[mi][ni] = f32x4{0.f,0.f,0.f,0.f};
    }

  auto compute = [&](int b) {
    #pragma unroll
    for (int ks = 0; ks < 2; ++ks) {
      const int kb = ks * 32 + l4 * 8;
      bf16x8 af[4], bgf[2], buf2[2];
      #pragma unroll
      for (int mi = 0; mi < 4; ++mi) af[mi] = *(const bf16x8*)&Al[b][wm*64 + mi*16 + l15][kb];
      #pragma unroll
      for (int ni = 0; ni < 2; ++ni) {
        bgf[ni]  = *(const bf16x8*)&Bgl[b][wn*32 + ni*16 + l15][kb];
        buf2[ni] = *(const bf16x8*)&Bul[b][wn*32 + ni*16 + l15][kb];
      }
      #pragma unroll
      for (int mi = 0; mi < 4; ++mi)
        #pragma unroll
        for (int ni = 0; ni < 2; ++ni) {
          accg[mi][ni] = __builtin_amdgcn_mfma_f32_16x16x32_bf16(af[mi], bgf[ni],  accg[mi][ni], 0, 0, 0);
          accu[mi][ni] = __builtin_amdgcn_mfma_f32_16x16x32_bf16(af[mi], buf2[ni], accu[mi][ni], 0, 0, 0);
        }
    }
  };

  constexpr int NK = H_ / BK;   // 32
  load_regs(0); write_lds(0); __syncthreads();
  int cur = 0;
  for (int kt = 0; kt < NK; ++kt) {
    if (kt + 1 < NK) load_regs((kt + 1) * BK);
    compute(cur);
    if (kt + 1 < NK) write_lds(cur ^ 1);
    __syncthreads();
    cur ^= 1;
  }

  // epilogue: silu(g)*u -> bf16 h[slot][i]
  #pragma unroll
  for (int mi = 0; mi < 4; ++mi)
    #pragma unroll
    for (int ni = 0; ni < 2; ++ni)
      #pragma unroll
      for (int j = 0; j < 4; ++j) {
        int rel = wm*64 + mi*16 + l4*4 + j;
        if (m0 + rel < cnt) {
          int col = n0 + wn*32 + ni*16 + l15;
          float g = accg[mi][ni][j];
          float u = accu[mi][ni][j];
          float hvv = (g / (1.0f + __expf(-g))) * u;
          hout[(size_t)(off + m0 + rel) * I_ + col] = (bf16_t)hvv;
        }
      }
}

// ================= GEMM2: h x w2^T -> per-slot partial (f32) =================
constexpr int B2M = 128, B2N = 128, B2K = 64;

__global__ __launch_bounds__(256, 2)
void gemm2_kernel(const bf16_t* __restrict__ hbuf, const float* __restrict__ w2,
                  const int* __restrict__ offs, const int* __restrict__ counts,
                  float* __restrict__ dpart)
{
  const int e = blockIdx.z;
  const int cnt = counts[e];
  const int m0 = blockIdx.x * B2M;
  if (m0 >= cnt) return;
  const int off = offs[e];
  const int n0 = blockIdx.y * B2N;
  const float* W = w2 + (size_t)e * ((size_t)H_ * I_) + (size_t)n0 * I_;

  __shared__ bf16_t Al[2][B2M][B2K];   // 32 KB
  __shared__ bf16_t Bl[2][B2N][B2K];   // 32 KB

  const int tid = threadIdx.x;
  const int lane = tid & 63, wid = tid >> 6;
  const int wm = wid >> 1, wn = wid & 1;
  const int l15 = lane & 15, l4 = lane >> 4;

  const bf16_t* asrc[4]; int arow_[4], akc_[4];
  #pragma unroll
  for (int c = 0; c < 4; ++c) {
    int q = tid + c * 256;
    int row = q >> 3, kc = q & 7;
    arow_[c] = row; akc_[c] = kc;
    int slot = off + m0 + row, mx = off + cnt - 1;
    if (slot > mx) slot = mx;
    asrc[c] = hbuf + (size_t)slot * I_ + kc * 8;
  }
  const float* bsrc[8]; int brow_[8], bkc_[8];
  #pragma unroll
  for (int c = 0; c < 8; ++c) {
    int q = tid + c * 256;               // 2048 chunks: row=q>>4, kc=q&15
    int row = q >> 4, kc = q & 15;
    brow_[c] = row; bkc_[c] = kc;
    bsrc[c] = W + (size_t)row * I_ + kc * 4;
  }

  int4 ar[4]; float4 br[8];
  auto load_regs = [&](int k0) {
    #pragma unroll
    for (int c = 0; c < 4; ++c) ar[c] = *(const int4*)(asrc[c] + k0);
    #pragma unroll
    for (int c = 0; c < 8; ++c) br[c] = *(const float4*)(bsrc[c] + k0);
  };
  auto write_lds = [&](int b) {
    #pragma unroll
    for (int c = 0; c < 4; ++c)
      *(int4*)&Al[b][arow_[c]][akc_[c] * 8] = ar[c];
    #pragma unroll
    for (int c = 0; c < 8; ++c) {
      bf16x4 t0; t0[0]=(bf16_t)br[c].x; t0[1]=(bf16_t)br[c].y; t0[2]=(bf16_t)br[c].z; t0[3]=(bf16_t)br[c].w;
      *(bf16x4*)&Bl[b][brow_[c]][bkc_[c] * 4] = t0;
    }
  };

  f32x4 acc[4][4];
  #pragma unroll
  for (int mi = 0; mi < 4; ++mi)
    #pragma unroll
    for (int ni = 0; ni < 4; ++ni) acc[mi][ni] = f32x4{0.f,0.f,0.f,0.f};

  auto compute = [&](int b) {
    #pragma unroll
    for (int ks = 0; ks < 2; ++ks) {
      const int kb = ks * 32 + l4 * 8;
      bf16x8 af[4], bf[4];
      #pragma unroll
      for (int mi = 0; mi < 4; ++mi) af[mi] = *(const bf16x8*)&Al[b][wm*64 + mi*16 + l15][kb];
      #pragma unroll
      for (int ni = 0; ni < 4; ++ni) bf[ni] = *(const bf16x8*)&Bl[b][wn*64 + ni*16 + l15][kb];
      #pragma unroll
      for (int mi = 0; mi < 4; ++mi)
        #pragma unroll
        for (int ni = 0; ni < 4; ++ni)
          acc[mi][ni] = __builtin_amdgcn_mfma_f32_16x16x32_bf16(af[mi], bf[ni], acc[mi][ni], 0, 0, 0);
    }
  };

  constexpr int NK = I_ / B2K;   // 88
  load_regs(0); write_lds(0); __syncthreads();
  int cur = 0;
  for (int kt = 0; kt < NK; ++kt) {
    if (kt + 1 < NK) load_regs((kt + 1) * B2K);
    compute(cur);
    if (kt + 1 < NK) write_lds(cur ^ 1);
    __syncthreads();
    cur ^= 1;
  }

  #pragma unroll
  for (int mi = 0; mi < 4; ++mi)
    #pragma unroll
    for (int ni = 0; ni < 4; ++ni)
      #pragma unroll
      for (int j = 0; j < 4; ++j) {
        int rel = wm*64 + mi*16 + l4*4 + j;
        if (m0 + rel < cnt) {
          int col = n0 + wn*64 + ni*16 + l15;
          dpart[(size_t)(off + m0 + rel) * H_ + col] = acc[mi][ni][j];
        }
      }
}

// ================= combine: out[t] = w0*d[s0] + w1*d[s1] =================
__global__ __launch_bounds__(256)
void combine_kernel(const float* __restrict__ dpart, const int* __restrict__ sot,
                    const float* __restrict__ tkw, float* __restrict__ out)
{
  int idx = blockIdx.x * 256 + threadIdx.x;     // T*H/4 total
  int t = idx >> 9;                              // H/4 = 512
  int c = (idx & 511) * 4;
  float wA = tkw[2*t], wB = tkw[2*t+1];
  int sA = sot[2*t], sB = sot[2*t+1];
  float4 a = *(const float4*)(dpart + (size_t)sA * H_ + c);
  float4 b = *(const float4*)(dpart + (size_t)sB * H_ + c);
  float4 o;
  o.x = wA*a.x + wB*b.x; o.y = wA*a.y + wB*b.y;
  o.z = wA*a.z + wB*b.z; o.w = wA*a.w + wB*b.w;
  *(float4*)(out + (size_t)t * H_ + c) = o;
}

extern "C" void kernel_launch(void* const* d_in, const int* in_sizes, int n_in,
                              void* d_out, int out_size, void* d_ws, size_t ws_size,
                              hipStream_t stream) {
  const float* hs = (const float*)d_in[0];
  const float* gw = (const float*)d_in[1];
  const float* w1 = (const float*)d_in[2];
  const float* w2 = (const float*)d_in[3];
  float* out = (float*)d_out;
  char* ws = (char*)d_ws;

  bf16_t* hb    = (bf16_t*)(ws + OFF_HB);
  bf16_t* hout  = (bf16_t*)(ws + OFF_HOUT);
  float*  dpart = (float*) (ws + OFF_DPART);
  int*    tos   = (int*)   (ws + OFF_TOS);
  int*    sot   = (int*)   (ws + OFF_SOT);
  int*    tki   = (int*)   (ws + OFF_TKI);
  float*  tkw   = (float*) (ws + OFF_TKW);
  int*    cnt   = (int*)   (ws + OFF_CNT);
  int*    offp  = (int*)   (ws + OFF_OFFS);
  int*    curp  = (int*)   (ws + OFF_CUR);

  hipMemsetAsync(ws + OFF_CNT, 0, 64, stream);   // zero expert counts each call

  router_kernel<<<T_, 256, 0, stream>>>(hs, gw, tki, tkw, cnt, hb);
  scan_kernel<<<1, 256, 0, stream>>>(cnt, tki, offp, curp, tos, sot);
  gemm1_kernel<<<dim3(T_ / BM, I_ / BNI, E_), 256, 0, stream>>>(hb, w1, tos, offp, cnt, hout);
  gemm2_kernel<<<dim3(T_ / B2M, H_ / B2N, E_), 256, 0, stream>>>(hout, w2, offp, cnt, dpart);
  combine_kernel<<<(T_ * H_ / 4) / 256, 256, 0, stream>>>(dpart, sot, tkw, out);
}